// Round 8
// baseline (279.802 us; speedup 1.0000x reference)
//
#include <hip/hip_runtime.h>
#include <stdint.h>

// Geometry (fixed): B=4, C=512, H=W=64
#define NB 4
#define CB 512
#define HH 64
#define WW 64
#define HW 4096
#define C4 2048
#define PTOT (NB*HW)   // 16384 pixels across batch

typedef float  f32x4  __attribute__((ext_vector_type(4)));
typedef short  bf16x8 __attribute__((ext_vector_type(8)));

__device__ __forceinline__ float relu_f(float v){ return v > 0.f ? v : 0.f; }

__device__ __forceinline__ float bf2f(unsigned short u){
    union { uint32_t i; float f; } v; v.i = ((uint32_t)u) << 16; return v.f;
}
__device__ __forceinline__ unsigned short f2bf(float f){
    union { float f; uint32_t i; } v; v.f = f;
    uint32_t r = v.i + 0x7FFFu + ((v.i >> 16) & 1u);   // RNE
    return (unsigned short)(r >> 16);
}

__device__ __forceinline__ void gload16(const void* g, void* l){
    __builtin_amdgcn_global_load_lds(
        (const __attribute__((address_space(1))) uint32_t*)g,
        (__attribute__((address_space(3))) uint32_t*)l, 16, 0, 0);
}

// ---------------------------------------------------------------------------
// fp32 -> bf16 cast of the three weight matrices in one launch.
// ---------------------------------------------------------------------------
__global__ __launch_bounds__(256) void cast3_f32_bf16(
    const float* __restrict__ a, unsigned short* __restrict__ oa,
    const float* __restrict__ b, unsigned short* __restrict__ ob,
    const float* __restrict__ c, unsigned short* __restrict__ oc)
{
    int i = blockIdx.x * 256 + threadIdx.x;
    const float* src; unsigned short* dst; int j;
    if (i < 65536)        { src = a; dst = oa; j = i; }
    else if (i < 327680)  { src = b; dst = ob; j = i - 65536; }
    else                  { src = c; dst = oc; j = i - 327680; }
    float4 v = ((const float4*)src)[j];
    ushort4 o;
    o.x = f2bf(v.x); o.y = f2bf(v.y); o.z = f2bf(v.z); o.w = f2bf(v.w);
    ((ushort4*)dst)[j] = o;
}

// ---------------------------------------------------------------------------
// x [b][c][p] fp32  ->  xT [b*HW + p][c] bf16   (64x64 LDS tile transpose)
// ---------------------------------------------------------------------------
__global__ __launch_bounds__(256) void transpose_cast_x(
    const float* __restrict__ x, unsigned short* __restrict__ xT)
{
    __shared__ unsigned short tile[64][72];
    const int b  = blockIdx.z;
    const int p0 = blockIdx.x * 64;
    const int c0 = blockIdx.y * 64;
    const int t  = threadIdx.x;

    const int pl = (t & 15) * 4;
    const int cl = t >> 4;
    const float* src = x + ((size_t)b * CB + c0) * HW + p0;
    #pragma unroll
    for (int r = 0; r < 4; r++) {
        int c = cl + r * 16;
        float4 v = *(const float4*)(src + (size_t)c * HW + pl);
        tile[pl + 0][c] = f2bf(v.x);
        tile[pl + 1][c] = f2bf(v.y);
        tile[pl + 2][c] = f2bf(v.z);
        tile[pl + 3][c] = f2bf(v.w);
    }
    __syncthreads();
    unsigned short* dst = xT + ((size_t)b * HW + p0) * CB + c0;
    const int cl2 = (t & 15) * 4;
    const int pl2 = t >> 4;
    #pragma unroll
    for (int r = 0; r < 4; r++) {
        int p = pl2 + r * 16;
        ushort4 o = *(ushort4*)&tile[p][cl2];
        *(ushort4*)(dst + (size_t)p * CB + cl2) = o;
    }
}

// ---------------------------------------------------------------------------
// Channel-last MFMA GEMM (R4 2-barrier structure + depth-2 A-prefetch + XCD
// swizzle):  D[p][o] = sum_k A[p][k] * Bw[o][k]  (bf16 in, f32 acc)
// Tile 128p x 128o, BK=64, 4 waves (256 thr), 4x4 16x16x32 frags/wave.
// LDS: 2 buffers x (A 16K | B 16K) = 64K static -> 2 blocks/CU.
//  - B (weights, L2-resident): gload_lds depth-1, pre-swizzled source.
//  - A (activations, HBM): reg-staged depth-2 (load t+2 to regs during tile t,
//    ds_write t+1 late in tile t) -> ~2 compute-phases of latency cover.
// vmcnt ledger (issue order per tile: B(t+1) gload x4, A(t+2) reg-load x4):
//   top of tile t:  outstanding [B(t),A(t+1)] -> vmcnt(4) waits B(t)
//   late in tile t: outstanding [A(t+1),B(t+1),A(t+2)] -> vmcnt(8) waits A(t+1)
// XCD swizzle: 4 o-tiles of each p-panel -> same XCD (A-panel L2 reuse x4).
// OUTMODE 0: bf16 [PTOT][512] channel-last; 1: fp32 [b][512][HW] + ReLU.
// ---------------------------------------------------------------------------
template<int K, int OUTMODE>
__global__ __launch_bounds__(256) void gemm_cl(
    const unsigned short* __restrict__ A,
    const unsigned short* __restrict__ Bw,
    void* __restrict__ out)
{
    __shared__ __align__(16) char lds[65536];

    const int t    = threadIdx.x;
    const int lane = t & 63;
    const int wid  = t >> 6;

    // XCD-chunked swizzle: nwg=512, 8 XCDs, 64 blocks/XCD chunk.
    const int lin = blockIdx.x + gridDim.x * blockIdx.y;   // default xcd = lin&7
    const int vl  = (lin & 7) * 64 + (lin >> 3);           // chunked, bijective
    const int p0  = (vl >> 2) * 128;
    const int o0  = (vl & 3) * 128;

    const int l15 = lane & 15;
    const int l4  = lane >> 4;
    const int wp  = (wid & 1) * 64;
    const int wo  = (wid >> 1) * 64;
    const int rowA = wp + l15;
    const int rowB = wo + l15;
    const int swzA = (rowA & 7) << 4;
    const int swzB = (rowB & 7) << 4;

    f32x4 acc[4][4];
    #pragma unroll
    for (int m = 0; m < 4; m++)
        #pragma unroll
        for (int n = 0; n < 4; n++) acc[m][n] = (f32x4)0.f;

    // ---- B staging: gload_lds, linear LDS dest, pre-swizzled global source
    auto B_STAGE = [&](int k0, char* base) {
        #pragma unroll
        for (int q = 0; q < 4; q++) {
            const int row = q * 32 + (t >> 3);
            const int kk  = k0 + ((((t & 7) * 16) ^ ((row & 7) << 4)) >> 1);
            gload16(Bw + (size_t)(o0 + row) * K + kk,
                    base + 16384 + q * 4096 + wid * 1024);
        }
    };

    // ---- A staging: global->regs (depth-2), ds_write swizzled (we control
    //      per-lane dest, unlike gload_lds). Thread t owns row t>>1, 64B half.
    const int arow  = t >> 1;            // 0..127
    const int acolb = (t & 1) * 64;      // byte col base within 128B row
    auto A_LOAD = [&](int k0, uint4 (&ar)[4]) {
        const unsigned short* src = A + (size_t)(p0 + arow) * K + k0 + (acolb >> 1);
        #pragma unroll
        for (int j = 0; j < 4; j++) ar[j] = *(const uint4*)(src + j * 8);
    };
    auto A_WRITE = [&](char* base, uint4 (&ar)[4]) {
        #pragma unroll
        for (int j = 0; j < 4; j++) {
            const int cb = acolb + j * 16;
            *(uint4*)(base + arow * 128 + (cb ^ ((arow & 7) << 4))) = ar[j];
        }
    };

    auto COMPUTE = [&](const char* base) {
        const char* cA = base;
        const char* cB = base + 16384;
        #pragma unroll
        for (int kh = 0; kh < 2; kh++) {
            const int colb = kh * 64 + l4 * 16;
            bf16x8 a[4], b[4];
            #pragma unroll
            for (int m = 0; m < 4; m++)
                a[m] = *(const bf16x8*)(cA + (rowA + m * 16) * 128 + (colb ^ swzA));
            #pragma unroll
            for (int n = 0; n < 4; n++)
                b[n] = *(const bf16x8*)(cB + (rowB + n * 16) * 128 + (colb ^ swzB));
            __builtin_amdgcn_s_setprio(1);
            #pragma unroll
            for (int m = 0; m < 4; m++)
                #pragma unroll
                for (int n = 0; n < 4; n++)
                    acc[m][n] = __builtin_amdgcn_mfma_f32_16x16x32_bf16(
                                    a[m], b[n], acc[m][n], 0, 0, 0);
            __builtin_amdgcn_s_setprio(0);
        }
    };

    const int NT = K / 64;
    uint4 arX[4], arY[4];

    // Prologue: tile 0 fully into buf0; A(1) into regs.
    B_STAGE(0, lds);
    A_LOAD(0, arX);
    asm volatile("s_waitcnt vmcnt(0)" ::: "memory");
    __builtin_amdgcn_sched_barrier(0);
    A_WRITE(lds, arX);
    A_LOAD(64, arX);                       // A(1) -> arX (4 loads in flight)
    asm volatile("s_waitcnt lgkmcnt(0)" ::: "memory");
    __builtin_amdgcn_sched_barrier(0);
    __builtin_amdgcn_s_barrier();

    // One tile: arT holds A(tt+1); arN receives A(tt+2).
    auto TILE = [&](int tt, char* cur, char* nxt, uint4 (&arT)[4], uint4 (&arN)[4]) {
        if (tt + 1 < NT) asm volatile("s_waitcnt vmcnt(4)" ::: "memory");
        else             asm volatile("s_waitcnt vmcnt(0)" ::: "memory");
        __builtin_amdgcn_sched_barrier(0);
        __builtin_amdgcn_s_barrier();
        __builtin_amdgcn_sched_barrier(0);

        if (tt + 1 < NT) B_STAGE((tt + 1) * 64, nxt);
        if (tt + 2 < NT) A_LOAD((tt + 2) * 64, arN);

        COMPUTE(cur);

        if (tt + 1 < NT) {
            if (tt + 2 < NT) asm volatile("s_waitcnt vmcnt(8)" ::: "memory");
            else             asm volatile("s_waitcnt vmcnt(4)" ::: "memory");
            __builtin_amdgcn_sched_barrier(0);
            A_WRITE(nxt, arT);
        }
        asm volatile("s_waitcnt lgkmcnt(0)" ::: "memory");
        __builtin_amdgcn_sched_barrier(0);
        __builtin_amdgcn_s_barrier();
    };

    #pragma unroll 1
    for (int tp = 0; tp < NT; tp += 2) {   // NT even (8 or 32)
        TILE(tp,     lds,         lds + 32768, arX, arY);
        TILE(tp + 1, lds + 32768, lds,         arY, arX);
    }

    if (OUTMODE == 0) {
        unsigned short* op = (unsigned short*)out;
        #pragma unroll
        for (int m = 0; m < 4; m++)
            #pragma unroll
            for (int r = 0; r < 4; r++) {
                const int p = p0 + wp + m * 16 + l4 * 4 + r;
                #pragma unroll
                for (int n = 0; n < 4; n++) {
                    const int o = wo + n * 16 + l15 + o0;
                    op[(size_t)p * CB + o] = f2bf(acc[m][n][r]);
                }
            }
    } else {
        __syncthreads();                   // protect LDS reuse vs last COMPUTE reads
        float (*tl)[132] = (float(*)[132])lds;
        const int bb   = p0 >> 12;
        const int phw0 = p0 & (HW - 1);
        #pragma unroll
        for (int half = 0; half < 2; half++) {
            if ((wid >> 1) == half) {
                #pragma unroll
                for (int n = 0; n < 4; n++)
                    #pragma unroll
                    for (int m = 0; m < 4; m++)
                        #pragma unroll
                        for (int r = 0; r < 4; r++)
                            tl[n * 16 + l15][wp + m * 16 + l4 * 4 + r] = acc[m][n][r];
            }
            __syncthreads();
            const int orow = t >> 2;
            const int pseg = (t & 3) * 32;
            float* dst = (float*)out +
                ((size_t)(bb * CB + o0 + half * 64 + orow)) * HW + phw0 + pseg;
            #pragma unroll
            for (int j = 0; j < 8; j++) {
                float4 v = *(float4*)&tl[orow][pseg + j * 4];
                v.x = relu_f(v.x); v.y = relu_f(v.y); v.z = relu_f(v.z); v.w = relu_f(v.w);
                *(float4*)(dst + j * 4) = v;
            }
            __syncthreads();
        }
    }
}

// ---------------------------------------------------------------------------
// Fused 4-direction IRNN scan, channel-last, scalar channel per thread.
// grid (512, 4): blockIdx.y = dir (0=u,1=r,2=d,3=l). Depth-8 reg prefetch.
// ---------------------------------------------------------------------------
__global__ __launch_bounds__(256) void irnn_fused(
    const unsigned short* __restrict__ in, unsigned short* __restrict__ outc,
    const float* __restrict__ wu, const float* __restrict__ bu,
    const float* __restrict__ wr, const float* __restrict__ br,
    const float* __restrict__ wd, const float* __restrict__ bd,
    const float* __restrict__ wl, const float* __restrict__ bl)
{
    const int dir = blockIdx.y;
    const float* wv; const float* bv; int pstep, rev;
    if      (dir == 0) { wv = wu; bv = bu; pstep = 64; rev = 1; }  // up
    else if (dir == 1) { wv = wr; bv = br; pstep = 1;  rev = 0; }  // right
    else if (dir == 2) { wv = wd; bv = bd; pstep = 64; rev = 0; }  // down
    else               { wv = wl; bv = bl; pstep = 1;  rev = 1; }  // left
    const int dirOff = dir * 512;

    const int idx = blockIdx.x * 256 + threadIdx.x;  // 0..131071
    const int c = idx & 511;
    const int f = (idx >> 9) & 63;
    const int b = idx >> 15;
    const int fbase = (pstep == 64) ? f : f * 64;

    const float wc = wv[c], bc = bv[c];
    const int t0 = rev ? 63 : 0;
    const int dp = rev ? -pstep : pstep;
    const int istep = dp * CB;
    const int ostep = dp * C4;

    const unsigned short* ip = in   + ((size_t)b * HW + fbase + (size_t)t0 * pstep) * CB + c;
    unsigned short*       op = outc + ((size_t)b * HW + fbase + (size_t)t0 * pstep) * C4 + dirOff + c;

    float s = relu_f(bf2f(ip[0]));
    op[0] = 0;

    unsigned short v0 = ip[1*istep], v1 = ip[2*istep], v2 = ip[3*istep], v3 = ip[4*istep],
                   v4 = ip[5*istep], v5 = ip[6*istep], v6 = ip[7*istep], v7 = ip[8*istep];

#define DO(kk, vv) { s = relu_f(fmaf(s, wc, bc + bf2f(vv))); op[(kk)*ostep] = f2bf(s); }
    for (int g = 0; g < 6; ++g) {
        const int k0 = 1 + 8 * g;
        DO(k0+0, v0); v0 = ip[(k0+ 8)*istep];
        DO(k0+1, v1); v1 = ip[(k0+ 9)*istep];
        DO(k0+2, v2); v2 = ip[(k0+10)*istep];
        DO(k0+3, v3); v3 = ip[(k0+11)*istep];
        DO(k0+4, v4); v4 = ip[(k0+12)*istep];
        DO(k0+5, v5); v5 = ip[(k0+13)*istep];
        DO(k0+6, v6); v6 = ip[(k0+14)*istep];
        DO(k0+7, v7); v7 = ip[(k0+15)*istep];
    }
    DO(49, v0); v0 = ip[57*istep];
    DO(50, v1); v1 = ip[58*istep];
    DO(51, v2); v2 = ip[59*istep];
    DO(52, v3); v3 = ip[60*istep];
    DO(53, v4); v4 = ip[61*istep];
    DO(54, v5); v5 = ip[62*istep];
    DO(55, v6); v6 = ip[63*istep];
    DO(56, v7);
    DO(57, v0); DO(58, v1); DO(59, v2); DO(60, v3);
    DO(61, v4); DO(62, v5); DO(63, v6);
#undef DO
}

// ---------------------------------------------------------------------------
// ws map: [0,16M) xT | [16M,80M) concat_T | [80M,96M) out0/mid |
//         [96M,..) bf16 weights. conv3x3 "attention" branch is dead -> skipped.
// ---------------------------------------------------------------------------
extern "C" void kernel_launch(void* const* d_in, const int* in_sizes, int n_in,
                              void* d_out, int out_size, void* d_ws, size_t ws_size,
                              hipStream_t stream) {
    const float* x     = (const float*)d_in[0];
    const float* cin_w = (const float*)d_in[7];
    const float* c2_w  = (const float*)d_in[8];
    const float* c3_w  = (const float*)d_in[9];
    const float* i1_wu = (const float*)d_in[10];
    const float* i1_bu = (const float*)d_in[11];
    const float* i1_wr = (const float*)d_in[12];
    const float* i1_br = (const float*)d_in[13];
    const float* i1_wd = (const float*)d_in[14];
    const float* i1_bd = (const float*)d_in[15];
    const float* i1_wl = (const float*)d_in[16];
    const float* i1_bl = (const float*)d_in[17];
    const float* i2_wu = (const float*)d_in[18];
    const float* i2_bu = (const float*)d_in[19];
    const float* i2_wr = (const float*)d_in[20];
    const float* i2_br = (const float*)d_in[21];
    const float* i2_wd = (const float*)d_in[22];
    const float* i2_bd = (const float*)d_in[23];
    const float* i2_wl = (const float*)d_in[24];
    const float* i2_bl = (const float*)d_in[25];

    char* ws = (char*)d_ws;
    unsigned short* xT     = (unsigned short*)(ws);
    unsigned short* concat = (unsigned short*)(ws + (size_t)16 * 1024 * 1024);
    unsigned short* mid    = (unsigned short*)(ws + (size_t)80 * 1024 * 1024);
    unsigned short* wA     = (unsigned short*)(ws + (size_t)96 * 1024 * 1024);
    unsigned short* wB     = (unsigned short*)(wA + 512 * 512);
    unsigned short* wC     = (unsigned short*)(wB + 512 * 2048);

    cast3_f32_bf16<<<2304, 256, 0, stream>>>(cin_w, wA, c2_w, wB, c3_w, wC);
    transpose_cast_x<<<dim3(HW/64, CB/64, NB), 256, 0, stream>>>(x, xT);

    dim3 ggrid(PTOT/128, 4);     // 128 x 4 = 512 blocks = 2/CU
    dim3 sgrid(512, 4);

    gemm_cl<512, 0><<<ggrid, 256, 0, stream>>>(xT, wA, mid);

    irnn_fused<<<sgrid, 256, 0, stream>>>(mid, concat,
        i1_wu, i1_bu, i1_wr, i1_br, i1_wd, i1_bd, i1_wl, i1_bl);

    gemm_cl<2048, 0><<<ggrid, 256, 0, stream>>>(concat, wB, mid);

    irnn_fused<<<sgrid, 256, 0, stream>>>(mid, concat,
        i2_wu, i2_bu, i2_wr, i2_br, i2_wd, i2_bd, i2_wl, i2_bl);

    gemm_cl<2048, 1><<<ggrid, 256, 0, stream>>>(concat, wC, d_out);
}

// Round 9
// 147.964 us; speedup vs baseline: 1.8910x; 1.8910x over previous
//
#include <hip/hip_runtime.h>
#include <stdint.h>

// Geometry (fixed): B=4, C=512, H=W=64
#define NB 4
#define CB 512
#define HH 64
#define WW 64
#define HW 4096
#define C4 2048
#define PTOT (NB*HW)   // 16384 pixels across batch

typedef float  f32x4  __attribute__((ext_vector_type(4)));
typedef short  bf16x8 __attribute__((ext_vector_type(8)));

__device__ __forceinline__ float relu_f(float v){ return v > 0.f ? v : 0.f; }

__device__ __forceinline__ float bf2f(unsigned short u){
    union { uint32_t i; float f; } v; v.i = ((uint32_t)u) << 16; return v.f;
}
__device__ __forceinline__ unsigned short f2bf(float f){
    union { float f; uint32_t i; } v; v.f = f;
    uint32_t r = v.i + 0x7FFFu + ((v.i >> 16) & 1u);   // RNE
    return (unsigned short)(r >> 16);
}

__device__ __forceinline__ void gload16(const void* g, void* l){
    __builtin_amdgcn_global_load_lds(
        (const __attribute__((address_space(1))) uint32_t*)g,
        (__attribute__((address_space(3))) uint32_t*)l, 16, 0, 0);
}

// ---------------------------------------------------------------------------
// fp32 -> bf16 cast of the three weight matrices in one launch.
// ---------------------------------------------------------------------------
__global__ __launch_bounds__(256) void cast3_f32_bf16(
    const float* __restrict__ a, unsigned short* __restrict__ oa,
    const float* __restrict__ b, unsigned short* __restrict__ ob,
    const float* __restrict__ c, unsigned short* __restrict__ oc)
{
    int i = blockIdx.x * 256 + threadIdx.x;
    const float* src; unsigned short* dst; int j;
    if (i < 65536)        { src = a; dst = oa; j = i; }
    else if (i < 327680)  { src = b; dst = ob; j = i - 65536; }
    else                  { src = c; dst = oc; j = i - 327680; }
    float4 v = ((const float4*)src)[j];
    ushort4 o;
    o.x = f2bf(v.x); o.y = f2bf(v.y); o.z = f2bf(v.z); o.w = f2bf(v.w);
    ((ushort4*)dst)[j] = o;
}

// ---------------------------------------------------------------------------
// x [b][c][p] fp32  ->  xT [b*HW + p][c] bf16   (64x64 LDS tile transpose)
// ---------------------------------------------------------------------------
__global__ __launch_bounds__(256) void transpose_cast_x(
    const float* __restrict__ x, unsigned short* __restrict__ xT)
{
    __shared__ unsigned short tile[64][72];
    const int b  = blockIdx.z;
    const int p0 = blockIdx.x * 64;
    const int c0 = blockIdx.y * 64;
    const int t  = threadIdx.x;

    const int pl = (t & 15) * 4;
    const int cl = t >> 4;
    const float* src = x + ((size_t)b * CB + c0) * HW + p0;
    #pragma unroll
    for (int r = 0; r < 4; r++) {
        int c = cl + r * 16;
        float4 v = *(const float4*)(src + (size_t)c * HW + pl);
        tile[pl + 0][c] = f2bf(v.x);
        tile[pl + 1][c] = f2bf(v.y);
        tile[pl + 2][c] = f2bf(v.z);
        tile[pl + 3][c] = f2bf(v.w);
    }
    __syncthreads();
    unsigned short* dst = xT + ((size_t)b * HW + p0) * CB + c0;
    const int cl2 = (t & 15) * 4;
    const int pl2 = t >> 4;
    #pragma unroll
    for (int r = 0; r < 4; r++) {
        int p = pl2 + r * 16;
        ushort4 o = *(ushort4*)&tile[p][cl2];
        *(ushort4*)(dst + (size_t)p * CB + cl2) = o;
    }
}

// ---------------------------------------------------------------------------
// Channel-last MFMA GEMM, 2-phase/K-tile, triple-buffer, counted vmcnt:
//   D[p][o] = sum_k A[p][k] * Bw[o][k]  (bf16 in, f32 acc)
// BM=128p x BN=256o, BK=64, 8 waves (2M x 4N), per-wave 64x64.
// grid (128,2) = 256 blocks = 1/CU. LDS: 3 x (A 16K | B 32K) = 144K dynamic,
// INTEGER offset rotation (no pointer arrays -> no scratch; R5/R6 lesson).
// Depth-2 prefetch: at top of tile t, 12 loads outstanding (t's 6 + t+1's 6),
// wait vmcnt(6); during t stage t+2's 6 (3 per phase). Never drains in-loop
// (m218: the counted wait IS the 8-phase gain; R7's drain-0 was the null).
// Phase = {8 ds_read_b128 ; 3 gload_lds ; lgkmcnt(0) ; SB ; setprio(1) ;
//          16 MFMA ; setprio(0)} ; barriers: top + mid only.
// amdgpu_waves_per_eu(2,2): exact occupancy -> 256-VGPR budget, no spill.
// OUTMODE 0: bf16 [PTOT][512] channel-last; 1: fp32 [b][512][HW] + ReLU.
// ---------------------------------------------------------------------------
template<int K, int OUTMODE>
__global__ __launch_bounds__(512) __attribute__((amdgpu_waves_per_eu(2, 2)))
void gemm_cl(
    const unsigned short* __restrict__ A,
    const unsigned short* __restrict__ Bw,
    void* __restrict__ out)
{
    extern __shared__ __align__(16) char lds[];

    const int t    = threadIdx.x;
    const int lane = t & 63;
    const int wid  = t >> 6;          // 0..7

    // XCD-chunked swizzle: 256 blocks, 8 XCDs, 32/chunk; the 2 o-blocks of a
    // p-panel are vl-adjacent -> same XCD -> A-panel L2 reuse.
    const int lin = blockIdx.x + (int)gridDim.x * blockIdx.y;   // 0..255
    const int vl  = (lin & 7) * 32 + (lin >> 3);                // bijective
    const int p0  = (vl >> 1) * 128;
    const int o0  = (vl & 1) * 256;

    const int l15 = lane & 15;
    const int l4  = lane >> 4;        // 0..3
    const int wm  = (wid >> 2) * 64;  // wave p-offset (0,64)
    const int wn  = (wid & 3) * 64;   // wave o-offset (0..192)
    const int swz = (l15 & 7) << 4;   // read-side XOR (row&7)<<4

    f32x4 acc[4][4];
    #pragma unroll
    for (int m = 0; m < 4; m++)
        #pragma unroll
        for (int n = 0; n < 4; n++) acc[m][n] = (f32x4)0.f;

    // staging decode: 64-row chunk per (region,j); lane -> row wid*8+sr
    const int sr  = lane >> 3;        // 0..7 == row&7
    const int scb = (lane & 7) * 16;  // byte col of granule
    const int skk = (scb ^ (sr << 4)) >> 1;   // pre-swizzled source k-elem off

    // part 0: A j=0,1 + B j=0 (3 loads); part 1: B j=1,2,3 (3 loads)
    auto STAGE3 = [&](int k0, int bufo, int part) {
        if (part == 0) {
            #pragma unroll
            for (int j = 0; j < 2; ++j)
                gload16(A + (size_t)(p0 + j * 64 + wid * 8 + sr) * K + k0 + skk,
                        lds + bufo + j * 8192 + wid * 1024);
            gload16(Bw + (size_t)(o0 + wid * 8 + sr) * K + k0 + skk,
                    lds + bufo + 16384 + wid * 1024);
        } else {
            #pragma unroll
            for (int j = 1; j < 4; ++j)
                gload16(Bw + (size_t)(o0 + j * 64 + wid * 8 + sr) * K + k0 + skk,
                        lds + bufo + 16384 + j * 8192 + wid * 1024);
        }
    };

#define PHASE(khv, part, dost, k2v, fov)                                       \
    {                                                                          \
        const int colb = (khv) * 64 + l4 * 16;                                 \
        bf16x8 af[4], bf[4];                                                   \
        _Pragma("unroll")                                                      \
        for (int m = 0; m < 4; ++m)                                            \
            af[m] = *(const bf16x8*)(lds + co + (wm + m * 16 + l15) * 128      \
                                     + (colb ^ swz));                          \
        _Pragma("unroll")                                                      \
        for (int n = 0; n < 4; ++n)                                            \
            bf[n] = *(const bf16x8*)(lds + co + 16384 +                        \
                                     (wn + n * 16 + l15) * 128 + (colb ^ swz));\
        if (dost) STAGE3(k2v, fov, part);                                      \
        asm volatile("s_waitcnt lgkmcnt(0)" ::: "memory");                     \
        __builtin_amdgcn_sched_barrier(0);                                     \
        __builtin_amdgcn_s_setprio(1);                                         \
        _Pragma("unroll")                                                      \
        for (int m = 0; m < 4; ++m)                                            \
            _Pragma("unroll")                                                  \
            for (int n = 0; n < 4; ++n)                                        \
                acc[m][n] = __builtin_amdgcn_mfma_f32_16x16x32_bf16(           \
                                af[m], bf[n], acc[m][n], 0, 0, 0);             \
        __builtin_amdgcn_s_setprio(0);                                         \
        __builtin_amdgcn_sched_barrier(0);                                     \
    }

    const int NT = K / 64;
    // prologue: tiles 0 and 1 (12 loads in flight)
    STAGE3(0, 0, 0);      STAGE3(0, 0, 1);
    STAGE3(64, 49152, 0); STAGE3(64, 49152, 1);

    int co = 0, no_ = 49152, fo = 98304;
    #pragma unroll 1
    for (int tt = 0; tt < NT; ++tt) {
        if (tt < NT - 1) asm volatile("s_waitcnt vmcnt(6)" ::: "memory");
        else             asm volatile("s_waitcnt vmcnt(0)" ::: "memory");
        __builtin_amdgcn_s_barrier();            // tile tt resident in co
        const bool st = (tt + 2 < NT);
        const int k2  = (tt + 2) * 64;

        PHASE(0, 0, st, k2, fo)
        __builtin_amdgcn_s_barrier();            // mid: keep waves aligned
        PHASE(1, 1, st, k2, fo)

        const int tmp = co; co = no_; no_ = fo; fo = tmp;
    }
#undef PHASE

    if (OUTMODE == 0) {
        unsigned short* op = (unsigned short*)out;
        #pragma unroll
        for (int m = 0; m < 4; m++)
            #pragma unroll
            for (int r = 0; r < 4; r++) {
                const int p = p0 + wm + m * 16 + l4 * 4 + r;
                #pragma unroll
                for (int n = 0; n < 4; n++) {
                    const int o = o0 + wn + n * 16 + l15;
                    op[(size_t)p * CB + o] = f2bf(acc[m][n][r]);
                }
            }
    } else {
        // fp32 channel-first + ReLU via LDS transpose, two o-halves of 128
        __syncthreads();
        float (*tl)[132] = (float(*)[132])lds;    // 128*132*4 = 67584 < 147456
        const int bb   = p0 >> 12;
        const int phw0 = p0 & (HW - 1);
        #pragma unroll
        for (int h = 0; h < 2; ++h) {
            if (((wid >> 1) & 1) == h) {
                #pragma unroll
                for (int n = 0; n < 4; n++)
                    #pragma unroll
                    for (int m = 0; m < 4; m++)
                        #pragma unroll
                        for (int r = 0; r < 4; r++)
                            tl[(wn & 127) + n * 16 + l15][wm + m * 16 + l4 * 4 + r]
                                = acc[m][n][r];
            }
            __syncthreads();
            const int orow = t >> 2;            // 0..127
            const int pseg = (t & 3) * 32;      // 0..96
            float* dst = (float*)out +
                ((size_t)(bb * CB + o0 + h * 128 + orow)) * HW + phw0 + pseg;
            #pragma unroll
            for (int j = 0; j < 8; j++) {
                float4 v = *(float4*)&tl[orow][pseg + j * 4];
                v.x = relu_f(v.x); v.y = relu_f(v.y); v.z = relu_f(v.z); v.w = relu_f(v.w);
                *(float4*)(dst + j * 4) = v;
            }
            __syncthreads();
        }
    }
}

// ---------------------------------------------------------------------------
// Fused 4-direction IRNN scan, channel-last, scalar channel per thread.
// grid (512, 4): blockIdx.y = dir (0=u,1=r,2=d,3=l). Depth-8 reg prefetch.
// ---------------------------------------------------------------------------
__global__ __launch_bounds__(256) void irnn_fused(
    const unsigned short* __restrict__ in, unsigned short* __restrict__ outc,
    const float* __restrict__ wu, const float* __restrict__ bu,
    const float* __restrict__ wr, const float* __restrict__ br,
    const float* __restrict__ wd, const float* __restrict__ bd,
    const float* __restrict__ wl, const float* __restrict__ bl)
{
    const int dir = blockIdx.y;
    const float* wv; const float* bv; int pstep, rev;
    if      (dir == 0) { wv = wu; bv = bu; pstep = 64; rev = 1; }  // up
    else if (dir == 1) { wv = wr; bv = br; pstep = 1;  rev = 0; }  // right
    else if (dir == 2) { wv = wd; bv = bd; pstep = 64; rev = 0; }  // down
    else               { wv = wl; bv = bl; pstep = 1;  rev = 1; }  // left
    const int dirOff = dir * 512;

    const int idx = blockIdx.x * 256 + threadIdx.x;  // 0..131071
    const int c = idx & 511;
    const int f = (idx >> 9) & 63;
    const int b = idx >> 15;
    const int fbase = (pstep == 64) ? f : f * 64;

    const float wc = wv[c], bc = bv[c];
    const int t0 = rev ? 63 : 0;
    const int dp = rev ? -pstep : pstep;
    const int istep = dp * CB;
    const int ostep = dp * C4;

    const unsigned short* ip = in   + ((size_t)b * HW + fbase + (size_t)t0 * pstep) * CB + c;
    unsigned short*       op = outc + ((size_t)b * HW + fbase + (size_t)t0 * pstep) * C4 + dirOff + c;

    float s = relu_f(bf2f(ip[0]));
    op[0] = 0;

    unsigned short v0 = ip[1*istep], v1 = ip[2*istep], v2 = ip[3*istep], v3 = ip[4*istep],
                   v4 = ip[5*istep], v5 = ip[6*istep], v6 = ip[7*istep], v7 = ip[8*istep];

#define DO(kk, vv) { s = relu_f(fmaf(s, wc, bc + bf2f(vv))); op[(kk)*ostep] = f2bf(s); }
    for (int g = 0; g < 6; ++g) {
        const int k0 = 1 + 8 * g;
        DO(k0+0, v0); v0 = ip[(k0+ 8)*istep];
        DO(k0+1, v1); v1 = ip[(k0+ 9)*istep];
        DO(k0+2, v2); v2 = ip[(k0+10)*istep];
        DO(k0+3, v3); v3 = ip[(k0+11)*istep];
        DO(k0+4, v4); v4 = ip[(k0+12)*istep];
        DO(k0+5, v5); v5 = ip[(k0+13)*istep];
        DO(k0+6, v6); v6 = ip[(k0+14)*istep];
        DO(k0+7, v7); v7 = ip[(k0+15)*istep];
    }
    DO(49, v0); v0 = ip[57*istep];
    DO(50, v1); v1 = ip[58*istep];
    DO(51, v2); v2 = ip[59*istep];
    DO(52, v3); v3 = ip[60*istep];
    DO(53, v4); v4 = ip[61*istep];
    DO(54, v5); v5 = ip[62*istep];
    DO(55, v6); v6 = ip[63*istep];
    DO(56, v7);
    DO(57, v0); DO(58, v1); DO(59, v2); DO(60, v3);
    DO(61, v4); DO(62, v5); DO(63, v6);
#undef DO
}

// ---------------------------------------------------------------------------
// ws map: [0,16M) xT | [16M,80M) concat_T | [80M,96M) out0/mid |
//         [96M,..) bf16 weights. conv3x3 "attention" branch is dead -> skipped.
// ---------------------------------------------------------------------------
extern "C" void kernel_launch(void* const* d_in, const int* in_sizes, int n_in,
                              void* d_out, int out_size, void* d_ws, size_t ws_size,
                              hipStream_t stream) {
    const float* x     = (const float*)d_in[0];
    const float* cin_w = (const float*)d_in[7];
    const float* c2_w  = (const float*)d_in[8];
    const float* c3_w  = (const float*)d_in[9];
    const float* i1_wu = (const float*)d_in[10];
    const float* i1_bu = (const float*)d_in[11];
    const float* i1_wr = (const float*)d_in[12];
    const float* i1_br = (const float*)d_in[13];
    const float* i1_wd = (const float*)d_in[14];
    const float* i1_bd = (const float*)d_in[15];
    const float* i1_wl = (const float*)d_in[16];
    const float* i1_bl = (const float*)d_in[17];
    const float* i2_wu = (const float*)d_in[18];
    const float* i2_bu = (const float*)d_in[19];
    const float* i2_wr = (const float*)d_in[20];
    const float* i2_br = (const float*)d_in[21];
    const float* i2_wd = (const float*)d_in[22];
    const float* i2_bd = (const float*)d_in[23];
    const float* i2_wl = (const float*)d_in[24];
    const float* i2_bl = (const float*)d_in[25];

    char* ws = (char*)d_ws;
    unsigned short* xT     = (unsigned short*)(ws);
    unsigned short* concat = (unsigned short*)(ws + (size_t)16 * 1024 * 1024);
    unsigned short* mid    = (unsigned short*)(ws + (size_t)80 * 1024 * 1024);
    unsigned short* wA     = (unsigned short*)(ws + (size_t)96 * 1024 * 1024);
    unsigned short* wB     = (unsigned short*)(wA + 512 * 512);
    unsigned short* wC     = (unsigned short*)(wB + 512 * 2048);

    cast3_f32_bf16<<<2304, 256, 0, stream>>>(cin_w, wA, c2_w, wB, c3_w, wC);
    transpose_cast_x<<<dim3(HW/64, CB/64, NB), 256, 0, stream>>>(x, xT);

    dim3 ggrid(PTOT/128, CB/256);    // 128 x 2 = 256 blocks = 1/CU
    dim3 sgrid(512, 4);
    const size_t GEMM_LDS = 147456;  // 3 x 48K triple buffer

    gemm_cl<512, 0><<<ggrid, 512, GEMM_LDS, stream>>>(xT, wA, mid);

    irnn_fused<<<sgrid, 256, 0, stream>>>(mid, concat,
        i1_wu, i1_bu, i1_wr, i1_br, i1_wd, i1_bd, i1_wl, i1_bl);

    gemm_cl<2048, 0><<<ggrid, 512, GEMM_LDS, stream>>>(concat, wB, mid);

    irnn_fused<<<sgrid, 256, 0, stream>>>(mid, concat,
        i2_wu, i2_bu, i2_wr, i2_br, i2_wd, i2_bd, i2_wl, i2_bl);

    gemm_cl<2048, 1><<<ggrid, 512, GEMM_LDS, stream>>>(concat, wC, d_out);
}

// Round 10
// 141.793 us; speedup vs baseline: 1.9733x; 1.0435x over previous
//
#include <hip/hip_runtime.h>
#include <stdint.h>

// Geometry (fixed): B=4, C=512, H=W=64
#define NB 4
#define CB 512
#define HH 64
#define WW 64
#define HW 4096
#define C4 2048
#define PTOT (NB*HW)   // 16384 pixels across batch

typedef float  f32x4  __attribute__((ext_vector_type(4)));
typedef short  bf16x8 __attribute__((ext_vector_type(8)));

__device__ __forceinline__ float relu_f(float v){ return v > 0.f ? v : 0.f; }

__device__ __forceinline__ float bf2f(unsigned short u){
    union { uint32_t i; float f; } v; v.i = ((uint32_t)u) << 16; return v.f;
}
__device__ __forceinline__ unsigned short f2bf(float f){
    union { float f; uint32_t i; } v; v.f = f;
    uint32_t r = v.i + 0x7FFFu + ((v.i >> 16) & 1u);   // RNE
    return (unsigned short)(r >> 16);
}

__device__ __forceinline__ void gload16(const void* g, void* l){
    __builtin_amdgcn_global_load_lds(
        (const __attribute__((address_space(1))) uint32_t*)g,
        (__attribute__((address_space(3))) uint32_t*)l, 16, 0, 0);
}

// ---------------------------------------------------------------------------
// Fused prep: blocks [0,2048) transpose+cast x -> xT ; blocks [2048,4352)
// cast the three weight matrices fp32 -> bf16 (one launch instead of two).
// ---------------------------------------------------------------------------
__global__ __launch_bounds__(256) void prep_fused(
    const float* __restrict__ x, unsigned short* __restrict__ xT,
    const float* __restrict__ a, unsigned short* __restrict__ oa,
    const float* __restrict__ b, unsigned short* __restrict__ ob,
    const float* __restrict__ c, unsigned short* __restrict__ oc)
{
    const int t = threadIdx.x;
    if (blockIdx.x >= 2048) {
        // ---- weight cast: 589824 float4 groups over 2304 blocks
        int i = (blockIdx.x - 2048) * 256 + t;
        const float* src; unsigned short* dst; int j;
        if (i < 65536)        { src = a; dst = oa; j = i; }
        else if (i < 327680)  { src = b; dst = ob; j = i - 65536; }
        else                  { src = c; dst = oc; j = i - 327680; }
        float4 v = ((const float4*)src)[j];
        ushort4 o;
        o.x = f2bf(v.x); o.y = f2bf(v.y); o.z = f2bf(v.z); o.w = f2bf(v.w);
        ((ushort4*)dst)[j] = o;
        return;
    }
    // ---- x [b][c][p] fp32 -> xT [b*HW+p][c] bf16, 64x64 LDS tile
    __shared__ unsigned short tile[64][72];
    const int tb = blockIdx.x;            // 0..2047
    const int p0 = (tb & 63) * 64;
    const int c0 = ((tb >> 6) & 7) * 64;
    const int bb = tb >> 9;

    const int pl = (t & 15) * 4;
    const int cl = t >> 4;
    const float* src = x + ((size_t)bb * CB + c0) * HW + p0;
    #pragma unroll
    for (int r = 0; r < 4; r++) {
        int c2 = cl + r * 16;
        float4 v = *(const float4*)(src + (size_t)c2 * HW + pl);
        tile[pl + 0][c2] = f2bf(v.x);
        tile[pl + 1][c2] = f2bf(v.y);
        tile[pl + 2][c2] = f2bf(v.z);
        tile[pl + 3][c2] = f2bf(v.w);
    }
    __syncthreads();
    unsigned short* dst = xT + ((size_t)bb * HW + p0) * CB + c0;
    const int cl2 = (t & 15) * 4;
    const int pl2 = t >> 4;
    #pragma unroll
    for (int r = 0; r < 4; r++) {
        int p = pl2 + r * 16;
        ushort4 o = *(ushort4*)&tile[p][cl2];
        *(ushort4*)(dst + (size_t)p * CB + cl2) = o;
    }
}

// ---------------------------------------------------------------------------
// Channel-last MFMA GEMM (R4 structure, the 9-round best):
//   D[p][o] = sum_k A[p][k] * Bw[o][k]  (bf16 in, f32 acc)
// Tile 128p x 128o, BK=64, 4 waves (256 thr), 4x4 16x16x32 frags/wave.
// LDS: 2 x (A 16K | B 16K) = 64K static -> 2 blocks/CU (the 2-block co-
// scheduling is what hides the staging latency at this shape; R5-R9's
// 8-wave phase-split ports all lost to it).
// Loop: STAGE(t+1) ; vmcnt(8) (drain only tile t's 8) ; barrier ; COMPUTE ;
// barrier. Grid (128,4): the 4 o-blocks of a p-panel are 128 apart in lin,
// 128%8==0 -> same XCD under default round-robin (A-panel L2 reuse for free).
// OUTMODE 0: bf16 [PTOT][512] channel-last; 1: fp32 [b][512][HW] + ReLU.
// ---------------------------------------------------------------------------
template<int K, int OUTMODE>
__global__ __launch_bounds__(256) void gemm_cl(
    const unsigned short* __restrict__ A,
    const unsigned short* __restrict__ Bw,
    void* __restrict__ out)
{
    __shared__ __align__(16) char lds[65536];

    const int t    = threadIdx.x;
    const int lane = t & 63;
    const int wid  = t >> 6;
    const int p0   = blockIdx.x * 128;
    const int o0   = blockIdx.y * 128;

    const int l15 = lane & 15;
    const int l4  = lane >> 4;
    const int wp  = (wid & 1) * 64;
    const int wo  = (wid >> 1) * 64;
    const int rowA = wp + l15;
    const int rowB = wo + l15;
    const int swzA = (rowA & 7) << 4;
    const int swzB = (rowB & 7) << 4;

    f32x4 acc[4][4];
    #pragma unroll
    for (int m = 0; m < 4; m++)
        #pragma unroll
        for (int n = 0; n < 4; n++) acc[m][n] = (f32x4)0.f;

    const int srow  = t >> 3;
    const int scolb = (t & 7) * 16;

    auto STAGE = [&](int k0, char* base) {
        #pragma unroll
        for (int q = 0; q < 4; q++) {
            const int row = q * 32 + srow;
            const int kk  = k0 + ((scolb ^ ((row & 7) << 4)) >> 1);
            gload16(A  + (size_t)(p0 + row) * K + kk, base +         q * 4096 + wid * 1024);
            gload16(Bw + (size_t)(o0 + row) * K + kk, base + 16384 + q * 4096 + wid * 1024);
        }
    };
    auto COMPUTE = [&](const char* base) {
        const char* cA = base;
        const char* cB = base + 16384;
        #pragma unroll
        for (int kh = 0; kh < 2; kh++) {
            const int colb = kh * 64 + l4 * 16;
            bf16x8 a[4], b[4];
            #pragma unroll
            for (int m = 0; m < 4; m++)
                a[m] = *(const bf16x8*)(cA + (rowA + m * 16) * 128 + (colb ^ swzA));
            #pragma unroll
            for (int n = 0; n < 4; n++)
                b[n] = *(const bf16x8*)(cB + (rowB + n * 16) * 128 + (colb ^ swzB));
            __builtin_amdgcn_s_setprio(1);
            #pragma unroll
            for (int m = 0; m < 4; m++)
                #pragma unroll
                for (int n = 0; n < 4; n++)
                    acc[m][n] = __builtin_amdgcn_mfma_f32_16x16x32_bf16(
                                    a[m], b[n], acc[m][n], 0, 0, 0);
            __builtin_amdgcn_s_setprio(0);
        }
    };

    const int NT = K / 64;
    STAGE(0, lds);                                  // 8 loads in flight
    #pragma unroll 2
    for (int tt = 0; tt < NT - 1; ++tt) {
        char* cbase = lds + ((tt & 1) ? 32768 : 0);
        char* nbase = lds + ((tt & 1) ? 0 : 32768);
        STAGE((tt + 1) * 64, nbase);                // +8 loads (tile t+1)
        asm volatile("s_waitcnt vmcnt(8)" ::: "memory");  // drain ONLY tile t's 8
        __builtin_amdgcn_s_barrier();               // tile t resident everywhere
        __builtin_amdgcn_sched_barrier(0);
        COMPUTE(cbase);                             // MFMA current (prefetch in flight)
        __builtin_amdgcn_s_barrier();               // all reads of cbase done
    }
    asm volatile("s_waitcnt vmcnt(0)" ::: "memory");
    __builtin_amdgcn_s_barrier();
    __builtin_amdgcn_sched_barrier(0);
    COMPUTE(lds + (((NT - 1) & 1) ? 32768 : 0));

    if (OUTMODE == 0) {
        unsigned short* op = (unsigned short*)out;
        #pragma unroll
        for (int m = 0; m < 4; m++)
            #pragma unroll
            for (int r = 0; r < 4; r++) {
                const int p = p0 + wp + m * 16 + l4 * 4 + r;
                #pragma unroll
                for (int n = 0; n < 4; n++) {
                    const int o = wo + n * 16 + l15 + o0;
                    op[(size_t)p * CB + o] = f2bf(acc[m][n][r]);
                }
            }
    } else {
        __syncthreads();                   // protect LDS reuse vs last COMPUTE reads
        float (*tl)[132] = (float(*)[132])lds;
        const int bb   = p0 >> 12;
        const int phw0 = p0 & (HW - 1);
        #pragma unroll
        for (int half = 0; half < 2; half++) {
            if ((wid >> 1) == half) {
                #pragma unroll
                for (int n = 0; n < 4; n++)
                    #pragma unroll
                    for (int m = 0; m < 4; m++)
                        #pragma unroll
                        for (int r = 0; r < 4; r++)
                            tl[n * 16 + l15][wp + m * 16 + l4 * 4 + r] = acc[m][n][r];
            }
            __syncthreads();
            const int orow = t >> 2;
            const int pseg = (t & 3) * 32;
            float* dst = (float*)out +
                ((size_t)(bb * CB + o0 + half * 64 + orow)) * HW + phw0 + pseg;
            #pragma unroll
            for (int j = 0; j < 8; j++) {
                float4 v = *(float4*)&tl[orow][pseg + j * 4];
                v.x = relu_f(v.x); v.y = relu_f(v.y); v.z = relu_f(v.z); v.w = relu_f(v.w);
                *(float4*)(dst + j * 4) = v;
            }
            __syncthreads();
        }
    }
}

// ---------------------------------------------------------------------------
// Fused 4-direction IRNN scan, channel-last, scalar channel per thread.
// grid (512, 4): blockIdx.y = dir (0=u,1=r,2=d,3=l). Depth-8 reg prefetch.
// Traffic: 4x16MB read (L3-resident) + 64MB write -> ~13 us, at BW floor.
// ---------------------------------------------------------------------------
__global__ __launch_bounds__(256) void irnn_fused(
    const unsigned short* __restrict__ in, unsigned short* __restrict__ outc,
    const float* __restrict__ wu, const float* __restrict__ bu,
    const float* __restrict__ wr, const float* __restrict__ br,
    const float* __restrict__ wd, const float* __restrict__ bd,
    const float* __restrict__ wl, const float* __restrict__ bl)
{
    const int dir = blockIdx.y;
    const float* wv; const float* bv; int pstep, rev;
    if      (dir == 0) { wv = wu; bv = bu; pstep = 64; rev = 1; }  // up
    else if (dir == 1) { wv = wr; bv = br; pstep = 1;  rev = 0; }  // right
    else if (dir == 2) { wv = wd; bv = bd; pstep = 64; rev = 0; }  // down
    else               { wv = wl; bv = bl; pstep = 1;  rev = 1; }  // left
    const int dirOff = dir * 512;

    const int idx = blockIdx.x * 256 + threadIdx.x;  // 0..131071
    const int c = idx & 511;
    const int f = (idx >> 9) & 63;
    const int b = idx >> 15;
    const int fbase = (pstep == 64) ? f : f * 64;

    const float wc = wv[c], bc = bv[c];
    const int t0 = rev ? 63 : 0;
    const int dp = rev ? -pstep : pstep;
    const int istep = dp * CB;
    const int ostep = dp * C4;

    const unsigned short* ip = in   + ((size_t)b * HW + fbase + (size_t)t0 * pstep) * CB + c;
    unsigned short*       op = outc + ((size_t)b * HW + fbase + (size_t)t0 * pstep) * C4 + dirOff + c;

    float s = relu_f(bf2f(ip[0]));
    op[0] = 0;

    unsigned short v0 = ip[1*istep], v1 = ip[2*istep], v2 = ip[3*istep], v3 = ip[4*istep],
                   v4 = ip[5*istep], v5 = ip[6*istep], v6 = ip[7*istep], v7 = ip[8*istep];

#define DO(kk, vv) { s = relu_f(fmaf(s, wc, bc + bf2f(vv))); op[(kk)*ostep] = f2bf(s); }
    for (int g = 0; g < 6; ++g) {
        const int k0 = 1 + 8 * g;
        DO(k0+0, v0); v0 = ip[(k0+ 8)*istep];
        DO(k0+1, v1); v1 = ip[(k0+ 9)*istep];
        DO(k0+2, v2); v2 = ip[(k0+10)*istep];
        DO(k0+3, v3); v3 = ip[(k0+11)*istep];
        DO(k0+4, v4); v4 = ip[(k0+12)*istep];
        DO(k0+5, v5); v5 = ip[(k0+13)*istep];
        DO(k0+6, v6); v6 = ip[(k0+14)*istep];
        DO(k0+7, v7); v7 = ip[(k0+15)*istep];
    }
    DO(49, v0); v0 = ip[57*istep];
    DO(50, v1); v1 = ip[58*istep];
    DO(51, v2); v2 = ip[59*istep];
    DO(52, v3); v3 = ip[60*istep];
    DO(53, v4); v4 = ip[61*istep];
    DO(54, v5); v5 = ip[62*istep];
    DO(55, v6); v6 = ip[63*istep];
    DO(56, v7);
    DO(57, v0); DO(58, v1); DO(59, v2); DO(60, v3);
    DO(61, v4); DO(62, v5); DO(63, v6);
#undef DO
}

// ---------------------------------------------------------------------------
// ws map: [0,16M) xT | [16M,80M) concat_T | [80M,96M) out0/mid |
//         [96M,..) bf16 weights. conv3x3 "attention" branch is dead -> skipped.
// 6 dispatches: prep | gemm512 | scan1 | gemm2048 | scan2 | gemm2048+relu.
// ---------------------------------------------------------------------------
extern "C" void kernel_launch(void* const* d_in, const int* in_sizes, int n_in,
                              void* d_out, int out_size, void* d_ws, size_t ws_size,
                              hipStream_t stream) {
    const float* x     = (const float*)d_in[0];
    const float* cin_w = (const float*)d_in[7];
    const float* c2_w  = (const float*)d_in[8];
    const float* c3_w  = (const float*)d_in[9];
    const float* i1_wu = (const float*)d_in[10];
    const float* i1_bu = (const float*)d_in[11];
    const float* i1_wr = (const float*)d_in[12];
    const float* i1_br = (const float*)d_in[13];
    const float* i1_wd = (const float*)d_in[14];
    const float* i1_bd = (const float*)d_in[15];
    const float* i1_wl = (const float*)d_in[16];
    const float* i1_bl = (const float*)d_in[17];
    const float* i2_wu = (const float*)d_in[18];
    const float* i2_bu = (const float*)d_in[19];
    const float* i2_wr = (const float*)d_in[20];
    const float* i2_br = (const float*)d_in[21];
    const float* i2_wd = (const float*)d_in[22];
    const float* i2_bd = (const float*)d_in[23];
    const float* i2_wl = (const float*)d_in[24];
    const float* i2_bl = (const float*)d_in[25];

    char* ws = (char*)d_ws;
    unsigned short* xT     = (unsigned short*)(ws);
    unsigned short* concat = (unsigned short*)(ws + (size_t)16 * 1024 * 1024);
    unsigned short* mid    = (unsigned short*)(ws + (size_t)80 * 1024 * 1024);
    unsigned short* wA     = (unsigned short*)(ws + (size_t)96 * 1024 * 1024);
    unsigned short* wB     = (unsigned short*)(wA + 512 * 512);
    unsigned short* wC     = (unsigned short*)(wB + 512 * 2048);

    // 1) prep: x transpose+cast AND weight casts in one launch
    prep_fused<<<4352, 256, 0, stream>>>(x, xT, cin_w, wA, c2_w, wB, c3_w, wC);

    dim3 ggrid(PTOT/128, 4);     // 128 x 4 = 512 blocks = 2/CU
    dim3 sgrid(512, 4);

    // 2) out0_T = xT @ cin_w^T
    gemm_cl<512, 0><<<ggrid, 256, 0, stream>>>(xT, wA, mid);

    // 3) IRNN #1 -> concat_T
    irnn_fused<<<sgrid, 256, 0, stream>>>(mid, concat,
        i1_wu, i1_bu, i1_wr, i1_br, i1_wd, i1_bd, i1_wl, i1_bl);

    // 4) mid_T = concat_T @ c2_w^T
    gemm_cl<2048, 0><<<ggrid, 256, 0, stream>>>(concat, wB, mid);

    // 5) IRNN #2 -> concat_T
    irnn_fused<<<sgrid, 256, 0, stream>>>(mid, concat,
        i2_wu, i2_bu, i2_wr, i2_br, i2_wd, i2_bd, i2_wl, i2_bl);

    // 6) d_out = relu(concat_T @ c3_w^T), fp32 channel-first
    gemm_cl<2048, 1><<<ggrid, 256, 0, stream>>>(concat, wC, d_out);
}